// Round 3
// baseline (214.646 us; speedup 1.0000x reference)
//
#include <hip/hip_runtime.h>
#include <hip/hip_bf16.h>
#include <stdint.h>

// Problem constants
#define BATCH 64
#define CH 3
#define HW 224
#define PP 7
#define GHW 32           // 32x32 patches
#define PD 147           // 7*7*3
#define DIM 1024
#define NTOK 65536       // 64 * 1024 tokens

typedef int   i32x4 __attribute__((ext_vector_type(4)));
typedef float f32x4v __attribute__((ext_vector_type(4)));

// ---------------- positional embedding table [1024][1024] ----------------
__global__ void pe_gen(float* __restrict__ pe) {
    int id = blockIdx.x * 256 + threadIdx.x;      // < 1048576
    int n = id >> 10, d = id & 1023;
    int yg = n >> 5, xg = n & 31;
    int quad = d >> 8, k = d & 255;
    float omega = exp2f(-13.287712379549449f * (float)k * (1.0f / 255.0f));
    float coord = (quad < 2) ? (float)xg : (float)yg;
    float arg = coord * omega;
    pe[id] = (quad & 1) ? cosf(arg) : sinf(arg);
}

// ---------------- mean|W| partial sums (deterministic) ----------------
__global__ void wabs(const float* __restrict__ W, float* __restrict__ part) {
    __shared__ float red[256];
    int t = threadIdx.x;
    int base = blockIdx.x * 1024;                 // 147 blocks * 1024 = 150528
    float s = fabsf(W[base + t]) + fabsf(W[base + t + 256]) +
              fabsf(W[base + t + 512]) + fabsf(W[base + t + 768]);
    red[t] = s;
    __syncthreads();
    for (int off = 128; off > 0; off >>= 1) {
        if (t < off) red[t] += red[t + off];
        __syncthreads();
    }
    if (t == 0) part[blockIdx.x] = red[0];
}

// ---------------- ternary weight quant -> int8, MFMA B layout ----------------
// Wq layout: [c = k>>4 (12)][d(1024)][j = k&15] int8, k padded to 192. 192 KB total.
__global__ void wquant(const float* __restrict__ W, const float* __restrict__ part,
                       float* __restrict__ swbuf, signed char* __restrict__ Wq) {
    __shared__ float red[256];
    int tid = threadIdx.x;
    red[tid] = (tid < 147) ? part[tid] : 0.f;
    __syncthreads();
    for (int off = 128; off > 0; off >>= 1) {
        if (tid < off) red[tid] += red[tid + off];
        __syncthreads();
    }
    float m = fmaxf(red[0] * (1.0f / 150528.0f), 1e-5f);
    float sw = 1.0f / m;
    if (blockIdx.x == 0 && tid == 0) swbuf[0] = m;   // dequant scale for gemm

    int e = blockIdx.x * 256 + tid;               // < 196608 = 1024*192
    int d = e / 192, k = e % 192;
    float t = 0.f;
    if (k < 147) {
        t = rintf(W[d * 147 + k] * sw);
        t = fminf(fmaxf(t, -1.f), 1.f);
    }
    Wq[(((k >> 4) << 10) | d) * 16 + (k & 15)] = (signed char)(int)t;
}

// ---------------- fused patchify + LN1 + int8 quant + i8 GEMM + LN2 + posemb ----------
// grid: 2048 blocks = (b, gh); block = 32 tokens x 1024 cols. 512 threads = 8 waves
// (2 wm x 4 wn); wave tile 16 rows x 256 cols = 16 acc frags (i32x4).
// K padded to 192 = 3 slices of 64 (i8 MFMA K=64); B staged in 6 rounds of 32 KB
// (kk, col-half) with T14 issue-early/write-late register staging.
// LDS (40064 B):
//   Bl   [0,     32768) : x-stage (18816 B fp32) then B round buffer [cc(4)][col'(512)][16]
//   A8   [32768, 38912) : quantized A int8, [c(12)][r(32)][j(16)]
//   stats[38912, 39936) : [rloc(32)][wn(4)][{sum,sq}] f32
//   sxl  [39936, 40064) : per-token dequant scale f32
__global__ __launch_bounds__(512, 4) void fused(
    const float* __restrict__ x, const float* __restrict__ g1,
    const float* __restrict__ b1, const signed char* __restrict__ Wq,
    const float* __restrict__ swbuf, const float* __restrict__ bproj,
    const float* __restrict__ g2, const float* __restrict__ b2,
    const float* __restrict__ pe, float* __restrict__ out) {
    extern __shared__ char lds[];
    float*       xs    = (float*)lds;
    i32x4*       Bl4   = (i32x4*)lds;
    signed char* A8    = (signed char*)(lds + 32768);
    const i32x4* A4    = (const i32x4*)(lds + 32768);
    float*       stats = (float*)(lds + 38912);
    float*       sxl   = (float*)(lds + 39936);

    int tid = threadIdx.x;
    int wave = tid >> 6, lane = tid & 63;
    int wm = wave >> 2, wn = wave & 3;
    int l15 = lane & 15, lg = lane >> 4;
    int blk = blockIdx.x;
    int b = blk >> 5, gh = blk & 31;

    const i32x4* Wq4 = (const i32x4*)Wq;

    // ---- prologue: issue B loads for round 0 (kk=0, h=0); land during phases 0/1 ----
    i32x4 st[4];
#pragma unroll
    for (int it = 0; it < 4; it++) {
        int j = tid + it * 512;                   // < 2048
        int cc = j >> 9, colp = j & 511;
        st[it] = Wq4[cc * 1024 + colp];           // kk=0, h=0
    }

    // ---- phase 0: coalesced x stage (21 rows of 224 floats, as float4) ----
    const f32x4v* x4 = (const f32x4v*)x;
    int base4 = b * 37632 + gh * 392;             // (b*150528 + gh*1568)/4
    f32x4v* xs4 = (f32x4v*)xs;
#pragma unroll
    for (int it = 0; it < 3; it++) {
        int j = tid + it * 512;
        if (j < 1176) {
            int c = j / 392, i4 = j - c * 392;
            xs4[c * 392 + i4] = x4[base4 + c * 12544 + i4];
        }
    }
    __syncthreads();

    // ---- phase 1: LN1 + per-token absmax int8 fake-quant -> A8 ----
    {
        int r = tid >> 4, sub = tid & 15;         // token r (=gw), k-slice sub
        float vals[12];
        float sum = 0.f, sq = 0.f;
#pragma unroll
        for (int i = 0; i < 12; i++) {
            int k = sub + (i << 4);
            float val = 0.f;
            if (k < 147) {
                int c = k % 3, pp = k / 3, p1 = pp / 7, p2 = pp % 7;
                val = xs[c * 1568 + p1 * 224 + r * 7 + p2];
            }
            vals[i] = val;
            sum += val; sq += val * val;
        }
#pragma unroll
        for (int m = 1; m < 16; m <<= 1) {
            sum += __shfl_xor(sum, m);
            sq  += __shfl_xor(sq, m);
        }
        float mu = sum * (1.0f / 147.0f);
        float rstd = rsqrtf(sq * (1.0f / 147.0f) - mu * mu + 1e-5f);
        float amax = 0.f;
#pragma unroll
        for (int i = 0; i < 12; i++) {
            int k = sub + (i << 4);
            if (k < 147) {
                float v = (vals[i] - mu) * rstd * g1[k] + b1[k];
                vals[i] = v;
                amax = fmaxf(amax, fabsf(v));
            }
        }
#pragma unroll
        for (int m = 1; m < 16; m <<= 1) amax = fmaxf(amax, __shfl_xor(amax, m));
        float mx = fmaxf(amax, 1e-5f);
        float sx = 127.0f / mx;
#pragma unroll
        for (int i = 0; i < 12; i++) {
            int k = sub + (i << 4);
            float q = 0.f;
            if (k < 147) q = fminf(fmaxf(rintf(vals[i] * sx), -128.f), 127.f);
            A8[(i * 32 + r) * 16 + sub] = (signed char)(int)q;
        }
        if (sub == 0) sxl[r] = mx * (1.0f / 127.0f);
    }

    // ---- phase 2: i8 GEMM, 6 rounds (3 k-slices x 2 col-halves), T14 staging ----
    i32x4 acc[16];
#pragma unroll
    for (int i = 0; i < 16; i++) acc[i] = (i32x4)0;

    for (int r = 0; r < 6; r++) {
        int kk = r >> 1;
        __syncthreads();                          // everyone done reading prev round / xs
#pragma unroll
        for (int it = 0; it < 4; it++) Bl4[tid + it * 512] = st[it];
        if (r < 5) {
            int kn = (r + 1) >> 1, hn = (r + 1) & 1;
#pragma unroll
            for (int it = 0; it < 4; it++) {
                int j = tid + it * 512;
                int cc = j >> 9, colp = j & 511;
                st[it] = Wq4[(kn * 4 + cc) * 1024 + hn * 512 + colp];
            }
        }
        __syncthreads();                          // B buffer ready
        i32x4 a = A4[(kk * 4 + lg) * 32 + wm * 16 + l15];
        int h = r & 1;
#pragma unroll
        for (int n = 0; n < 8; n++) {
            i32x4 bf = Bl4[lg * 512 + wn * 128 + n * 16 + l15];
            acc[h * 8 + n] = __builtin_amdgcn_mfma_i32_16x16x64_i8(a, bf, acc[h * 8 + n], 0, 0, 0);
        }
    }

    // ---- phase 3: epilogue — dequant + bias, LN2 over 1024 cols, + posemb ----
    float inv_sw = swbuf[0];
    float sc[4];
    int rloc[4];
#pragma unroll
    for (int rr = 0; rr < 4; rr++) {
        rloc[rr] = wm * 16 + lg * 4 + rr;
        sc[rr] = sxl[rloc[rr]] * inv_sw;
    }
    float fa[16][4];
    float s[4] = {0.f, 0.f, 0.f, 0.f}, q[4] = {0.f, 0.f, 0.f, 0.f};
#pragma unroll
    for (int h = 0; h < 2; h++)
#pragma unroll
    for (int n = 0; n < 8; n++) {
        int idx = h * 8 + n;
        int col = h * 512 + wn * 128 + n * 16 + l15;
        float bp = bproj[col];
#pragma unroll
        for (int rr = 0; rr < 4; rr++) {
            float v = (float)acc[idx][rr] * sc[rr] + bp;
            fa[idx][rr] = v;
            s[rr] += v; q[rr] += v * v;
        }
    }
#pragma unroll
    for (int m = 1; m < 16; m <<= 1) {
#pragma unroll
        for (int rr = 0; rr < 4; rr++) {
            s[rr] += __shfl_xor(s[rr], m);
            q[rr] += __shfl_xor(q[rr], m);
        }
    }
    if (l15 == 0) {
#pragma unroll
        for (int rr = 0; rr < 4; rr++) {
            stats[(rloc[rr] * 4 + wn) * 2 + 0] = s[rr];
            stats[(rloc[rr] * 4 + wn) * 2 + 1] = q[rr];
        }
    }
    __syncthreads();

    float mean[4], rstd2[4];
#pragma unroll
    for (int rr = 0; rr < 4; rr++) {
        float st2 = 0.f, qt = 0.f;
#pragma unroll
        for (int w = 0; w < 4; w++) {
            st2 += stats[(rloc[rr] * 4 + w) * 2 + 0];
            qt  += stats[(rloc[rr] * 4 + w) * 2 + 1];
        }
        float mu = st2 * (1.0f / 1024.0f);
        mean[rr] = mu;
        rstd2[rr] = rsqrtf(qt * (1.0f / 1024.0f) - mu * mu + 1e-5f);
    }

#pragma unroll
    for (int h = 0; h < 2; h++)
#pragma unroll
    for (int n = 0; n < 8; n++) {
        int idx = h * 8 + n;
        int col = h * 512 + wn * 128 + n * 16 + l15;
        float gg = g2[col], bb = b2[col];
#pragma unroll
        for (int rr = 0; rr < 4; rr++) {
            int row = blk * 32 + rloc[rr];
            int nimg = gh * 32 + rloc[rr];
            float o = (fa[idx][rr] - mean[rr]) * rstd2[rr] * gg + bb + pe[nimg * 1024 + col];
            out[(size_t)row * 1024 + col] = o;
        }
    }
}

extern "C" void kernel_launch(void* const* d_in, const int* in_sizes, int n_in,
                              void* d_out, int out_size, void* d_ws, size_t ws_size,
                              hipStream_t stream) {
    const float* x     = (const float*)d_in[0];
    const float* ln1_g = (const float*)d_in[1];
    const float* ln1_b = (const float*)d_in[2];
    const float* W     = (const float*)d_in[3];
    const float* bproj = (const float*)d_in[4];
    const float* ln2_g = (const float*)d_in[5];
    const float* ln2_b = (const float*)d_in[6];
    float* out = (float*)d_out;

    // workspace layout
    char* ws = (char*)d_ws;
    float*       pe    = (float*)ws;                           // 4 MB
    signed char* Wq    = (signed char*)(ws + (4u << 20));      // 196,608 B
    float*       part  = (float*)(ws + (4u << 20) + 196608u);  // 147 floats
    float*       swbuf = part + 160;

    pe_gen<<<4096, 256, 0, stream>>>(pe);
    wabs<<<147, 256, 0, stream>>>(W, part);
    wquant<<<768, 256, 0, stream>>>(W, part, swbuf, Wq);
    fused<<<2048, 512, 40064, stream>>>(x, ln1_g, ln1_b, Wq, swbuf, bproj,
                                        ln2_g, ln2_b, pe, out);
}

// Round 4
// 155.439 us; speedup vs baseline: 1.3809x; 1.3809x over previous
//
#include <hip/hip_runtime.h>
#include <hip/hip_bf16.h>
#include <stdint.h>

// Problem constants
#define BATCH 64
#define CH 3
#define HW 224
#define PP 7
#define GHW 32           // 32x32 patches
#define PD 147           // 7*7*3
#define DIM 1024
#define NTOK 65536       // 64 * 1024 tokens

typedef int   i32x4 __attribute__((ext_vector_type(4)));
typedef float f32x4v __attribute__((ext_vector_type(4)));

// ---------------- positional embedding table [1024][1024] ----------------
__global__ void pe_gen(float* __restrict__ pe) {
    int id = blockIdx.x * 256 + threadIdx.x;      // < 1048576
    int n = id >> 10, d = id & 1023;
    int yg = n >> 5, xg = n & 31;
    int quad = d >> 8, k = d & 255;
    float omega = exp2f(-13.287712379549449f * (float)k * (1.0f / 255.0f));
    float coord = (quad < 2) ? (float)xg : (float)yg;
    float arg = coord * omega;
    pe[id] = (quad & 1) ? cosf(arg) : sinf(arg);
}

// ---------------- mean|W| partial sums (deterministic) ----------------
__global__ void wabs(const float* __restrict__ W, float* __restrict__ part) {
    __shared__ float red[256];
    int t = threadIdx.x;
    int base = blockIdx.x * 1024;                 // 147 blocks * 1024 = 150528
    float s = fabsf(W[base + t]) + fabsf(W[base + t + 256]) +
              fabsf(W[base + t + 512]) + fabsf(W[base + t + 768]);
    red[t] = s;
    __syncthreads();
    for (int off = 128; off > 0; off >>= 1) {
        if (t < off) red[t] += red[t + off];
        __syncthreads();
    }
    if (t == 0) part[blockIdx.x] = red[0];
}

// ---------------- ternary weight quant -> int8, MFMA B layout ----------------
// Wq layout: [c = k>>4 (12)][d(1024)][j = k&15] int8, k padded to 192. 192 KB total.
__global__ void wquant(const float* __restrict__ W, const float* __restrict__ part,
                       float* __restrict__ swbuf, signed char* __restrict__ Wq) {
    __shared__ float red[256];
    int tid = threadIdx.x;
    red[tid] = (tid < 147) ? part[tid] : 0.f;
    __syncthreads();
    for (int off = 128; off > 0; off >>= 1) {
        if (tid < off) red[tid] += red[tid + off];
        __syncthreads();
    }
    float m = fmaxf(red[0] * (1.0f / 150528.0f), 1e-5f);
    float sw = 1.0f / m;
    if (blockIdx.x == 0 && tid == 0) swbuf[0] = m;   // dequant scale for gemm

    int e = blockIdx.x * 256 + tid;               // < 196608 = 1024*192
    int d = e / 192, k = e % 192;
    float t = 0.f;
    if (k < 147) {
        t = rintf(W[d * 147 + k] * sw);
        t = fminf(fmaxf(t, -1.f), 1.f);
    }
    Wq[(((k >> 4) << 10) | d) * 16 + (k & 15)] = (signed char)(int)t;
}

// ---------------- fused patchify + LN1 + int8 quant + i8 GEMM + LN2 + posemb ----------
// grid: 2048 blocks; logical id = XCD-swizzled, gh-major: each XCD owns 4 gh values
// (pe slice 512 KB, L2-resident). Block = 32 tokens x 1024 cols. 512 threads = 8 waves
// (2 wm x 4 wn); wave tile 16 rows x 256 cols = 16 acc frags (i32x4).
// K padded to 192 = 3 slices of 64 (i8 MFMA K=64); B staged in 6 FULLY-UNROLLED rounds
// of 32 KB with issue-early/write-late register staging (T14). All acc indexing is
// compile-time (rule #20). Epilogue floats are bit-cast back into acc (no extra regs).
// LDS (40064 B):
//   Bl   [0,     32768) : x-stage (18816 B fp32) then B round buffer [cc(4)][col'(512)][16]
//   A8   [32768, 38912) : quantized A int8, [c(12)][r(32)][j(16)]
//   stats[38912, 39936) : [rloc(32)][wn(4)][{sum,sq}] f32
//   sxl  [39936, 40064) : per-token dequant scale f32
__global__ __launch_bounds__(512, 4) void fused(
    const float* __restrict__ x, const float* __restrict__ g1,
    const float* __restrict__ b1, const signed char* __restrict__ Wq,
    const float* __restrict__ swbuf, const float* __restrict__ bproj,
    const float* __restrict__ g2, const float* __restrict__ b2,
    const float* __restrict__ pe, float* __restrict__ out) {
    extern __shared__ char lds[];
    float*       xs    = (float*)lds;
    i32x4*       Bl4   = (i32x4*)lds;
    signed char* A8    = (signed char*)(lds + 32768);
    const i32x4* A4    = (const i32x4*)(lds + 32768);
    float*       stats = (float*)(lds + 38912);
    float*       sxl   = (float*)(lds + 39936);

    int tid = threadIdx.x;
    int wave = tid >> 6, lane = tid & 63;
    int wm = wave >> 2, wn = wave & 3;
    int l15 = lane & 15, lg = lane >> 4;

    // XCD-swizzled, gh-major mapping: XCD x owns logical blocks [x*256, x*256+256)
    int lblk = (blockIdx.x & 7) * 256 + (blockIdx.x >> 3);
    int gh = lblk >> 6, b = lblk & 63;
    int rowbase = b * 1024 + gh * 32;             // output token base

    const i32x4* Wq4 = (const i32x4*)Wq;

    // ---- phase 0: coalesced x stage (21 rows of 224 floats, as float4) ----
    const f32x4v* x4 = (const f32x4v*)x;
    int base4 = b * 37632 + gh * 392;             // (b*150528 + gh*1568)/4
    f32x4v* xs4 = (f32x4v*)xs;
    f32x4v xv[3];
#pragma unroll
    for (int it = 0; it < 3; it++) {
        int j = tid + it * 512;
        if (j < 1176) {
            int c = j / 392, i4 = j - c * 392;
            xv[it] = x4[base4 + c * 12544 + i4];
        }
    }

    // ---- prologue: issue B loads for round 0 (kk=0, h=0); land during phases 0/1 ----
    i32x4 st[4];
#pragma unroll
    for (int it = 0; it < 4; it++) {
        int j = tid + it * 512;                   // < 2048
        int cc = j >> 9, colp = j & 511;
        st[it] = Wq4[cc * 1024 + colp];           // kk=0, h=0
    }

#pragma unroll
    for (int it = 0; it < 3; it++) {
        int j = tid + it * 512;
        if (j < 1176) {
            int c = j / 392, i4 = j - c * 392;
            xs4[c * 392 + i4] = xv[it];
        }
    }
    __syncthreads();

    // ---- phase 1: LN1 + per-token absmax int8 fake-quant -> A8 ----
    {
        int r = tid >> 4, sub = tid & 15;         // token r (=gw), k-slice sub
        float vals[12];
        float sum = 0.f, sq = 0.f;
#pragma unroll
        for (int i = 0; i < 12; i++) {
            int k = sub + (i << 4);
            float val = 0.f;
            if (k < 147) {
                int c = k % 3, pp = k / 3, p1 = pp / 7, p2 = pp % 7;
                val = xs[c * 1568 + p1 * 224 + r * 7 + p2];
            }
            vals[i] = val;
            sum += val; sq += val * val;
        }
#pragma unroll
        for (int m = 1; m < 16; m <<= 1) {
            sum += __shfl_xor(sum, m);
            sq  += __shfl_xor(sq, m);
        }
        float mu = sum * (1.0f / 147.0f);
        float rstd = rsqrtf(sq * (1.0f / 147.0f) - mu * mu + 1e-5f);
        float amax = 0.f;
#pragma unroll
        for (int i = 0; i < 12; i++) {
            int k = sub + (i << 4);
            if (k < 147) {
                float v = (vals[i] - mu) * rstd * g1[k] + b1[k];
                vals[i] = v;
                amax = fmaxf(amax, fabsf(v));
            }
        }
#pragma unroll
        for (int m = 1; m < 16; m <<= 1) amax = fmaxf(amax, __shfl_xor(amax, m));
        float mx = fmaxf(amax, 1e-5f);
        float sx = 127.0f / mx;
#pragma unroll
        for (int i = 0; i < 12; i++) {
            int k = sub + (i << 4);
            float q = 0.f;
            if (k < 147) q = fminf(fmaxf(rintf(vals[i] * sx), -128.f), 127.f);
            A8[(i * 32 + r) * 16 + sub] = (signed char)(int)q;
        }
        if (sub == 0) sxl[r] = mx * (1.0f / 127.0f);
    }

    // ---- phase 2: i8 GEMM, 6 unrolled rounds (3 k-slices x 2 col-halves) ----
    i32x4 acc[16];
#pragma unroll
    for (int i = 0; i < 16; i++) acc[i] = (i32x4)0;

#pragma unroll
    for (int r = 0; r < 6; r++) {
        const int kk = r >> 1;
        const int h = r & 1;
        __syncthreads();                          // prev round reads / xs reads done
#pragma unroll
        for (int it = 0; it < 4; it++) Bl4[tid + it * 512] = st[it];
        if (r < 5) {
            const int kn = (r + 1) >> 1, hn = (r + 1) & 1;
#pragma unroll
            for (int it = 0; it < 4; it++) {
                int j = tid + it * 512;
                int cc = j >> 9, colp = j & 511;
                st[it] = Wq4[(kn * 4 + cc) * 1024 + hn * 512 + colp];
            }
        }
        __syncthreads();                          // B buffer ready
        i32x4 a = A4[(kk * 4 + lg) * 32 + wm * 16 + l15];
#pragma unroll
        for (int n = 0; n < 8; n++) {
            i32x4 bf = Bl4[lg * 512 + wn * 128 + n * 16 + l15];
            acc[h * 8 + n] = __builtin_amdgcn_mfma_i32_16x16x64_i8(a, bf, acc[h * 8 + n], 0, 0, 0);
        }
    }

    // ---- phase 3: epilogue — dequant + bias, LN2 over 1024 cols, + posemb ----
    float inv_sw = swbuf[0];
    float sc[4];
    int rloc[4];
#pragma unroll
    for (int rr = 0; rr < 4; rr++) {
        rloc[rr] = wm * 16 + lg * 4 + rr;
        sc[rr] = sxl[rloc[rr]] * inv_sw;
    }
    float s[4] = {0.f, 0.f, 0.f, 0.f}, q[4] = {0.f, 0.f, 0.f, 0.f};
#pragma unroll
    for (int h = 0; h < 2; h++)
#pragma unroll
    for (int n = 0; n < 8; n++) {
        const int idx = h * 8 + n;
        int col = h * 512 + wn * 128 + n * 16 + l15;
        float bp = bproj[col];
#pragma unroll
        for (int rr = 0; rr < 4; rr++) {
            float v = (float)acc[idx][rr] * sc[rr] + bp;
            acc[idx][rr] = __float_as_int(v);     // bit-cast in place, no extra regs
            s[rr] += v; q[rr] += v * v;
        }
    }
#pragma unroll
    for (int m = 1; m < 16; m <<= 1) {
#pragma unroll
        for (int rr = 0; rr < 4; rr++) {
            s[rr] += __shfl_xor(s[rr], m);
            q[rr] += __shfl_xor(q[rr], m);
        }
    }
    if (l15 == 0) {
#pragma unroll
        for (int rr = 0; rr < 4; rr++) {
            stats[(rloc[rr] * 4 + wn) * 2 + 0] = s[rr];
            stats[(rloc[rr] * 4 + wn) * 2 + 1] = q[rr];
        }
    }
    __syncthreads();

    float mean[4], rstd2[4];
#pragma unroll
    for (int rr = 0; rr < 4; rr++) {
        float st2 = 0.f, qt = 0.f;
#pragma unroll
        for (int w = 0; w < 4; w++) {
            st2 += stats[(rloc[rr] * 4 + w) * 2 + 0];
            qt  += stats[(rloc[rr] * 4 + w) * 2 + 1];
        }
        float mu = st2 * (1.0f / 1024.0f);
        mean[rr] = mu;
        rstd2[rr] = rsqrtf(qt * (1.0f / 1024.0f) - mu * mu + 1e-5f);
    }

#pragma unroll
    for (int h = 0; h < 2; h++)
#pragma unroll
    for (int n = 0; n < 8; n++) {
        const int idx = h * 8 + n;
        int col = h * 512 + wn * 128 + n * 16 + l15;
        float gg = g2[col], bb = b2[col];
#pragma unroll
        for (int rr = 0; rr < 4; rr++) {
            int row = rowbase + rloc[rr];
            int nimg = gh * 32 + rloc[rr];
            float v = __int_as_float(acc[idx][rr]);
            float o = (v - mean[rr]) * rstd2[rr] * gg + bb + pe[nimg * 1024 + col];
            __builtin_nontemporal_store(o, &out[(size_t)row * 1024 + col]);
        }
    }
}

extern "C" void kernel_launch(void* const* d_in, const int* in_sizes, int n_in,
                              void* d_out, int out_size, void* d_ws, size_t ws_size,
                              hipStream_t stream) {
    const float* x     = (const float*)d_in[0];
    const float* ln1_g = (const float*)d_in[1];
    const float* ln1_b = (const float*)d_in[2];
    const float* W     = (const float*)d_in[3];
    const float* bproj = (const float*)d_in[4];
    const float* ln2_g = (const float*)d_in[5];
    const float* ln2_b = (const float*)d_in[6];
    float* out = (float*)d_out;

    // workspace layout
    char* ws = (char*)d_ws;
    float*       pe    = (float*)ws;                           // 4 MB
    signed char* Wq    = (signed char*)(ws + (4u << 20));      // 196,608 B
    float*       part  = (float*)(ws + (4u << 20) + 196608u);  // 147 floats
    float*       swbuf = part + 160;

    pe_gen<<<4096, 256, 0, stream>>>(pe);
    wabs<<<147, 256, 0, stream>>>(W, part);
    wquant<<<768, 256, 0, stream>>>(W, part, swbuf, Wq);
    fused<<<2048, 512, 40064, stream>>>(x, ln1_g, ln1_b, Wq, swbuf, bproj,
                                        ln2_g, ln2_b, pe, out);
}